// Round 9
// baseline (997.530 us; speedup 1.0000x reference)
//
#include <hip/hip_runtime.h>

#define NN 100000
#define RR 1000
#define DD 64
#define EE 200
#define BB 256
#define WW 5
#define TT 5
#define E2 400
#define E4 800
#define NT 1024

__device__ __forceinline__ float sigf(float x) { return 1.0f / (1.0f + expf(-x)); }

// One MLP layer: dst = relu(src @ Wm + bias), K-split x2 over 800 threads,
// register double-buffered weight prefetch (all indices compile-time).
template<int NW>
__device__ __forceinline__ void mlp_layer(const float* __restrict__ Wm,
                                          const float* __restrict__ bias,
                                          float (&src)[WW][E2],
                                          float (&part)[WW][2][E2],
                                          float (&dst)[WW][E2],
                                          int tid)
{
    if (tid < 2*E2) {
        const int half = tid / E2;          // 0..1
        const int n    = tid - half*E2;     // 0..399
        const int k0   = half * (E2/2);     // 0 or 200
        const float* wp = Wm + (size_t)k0*E2 + n;
        float acc[NW];
        #pragma unroll
        for (int w = 0; w < NW; ++w) acc[w] = 0.0f;
        float wc[8], wn[8];
        #pragma unroll
        for (int i = 0; i < 8; ++i) wc[i] = wp[i*E2];
        int k = k0;
        for (int kk = 0; kk < (E2/2)/8 - 1; ++kk) {     // 24 pipelined chunks
            wp += 8*E2;
            #pragma unroll
            for (int i = 0; i < 8; ++i) wn[i] = wp[i*E2];
            #pragma unroll
            for (int w = 0; w < NW; ++w) {
                float4 a = *(const float4*)&src[w][k];
                float4 c = *(const float4*)&src[w][k+4];
                acc[w] += a.x*wc[0] + a.y*wc[1] + a.z*wc[2] + a.w*wc[3]
                        + c.x*wc[4] + c.y*wc[5] + c.z*wc[6] + c.w*wc[7];
            }
            #pragma unroll
            for (int i = 0; i < 8; ++i) wc[i] = wn[i];
            k += 8;
        }
        #pragma unroll
        for (int w = 0; w < NW; ++w) {                  // final chunk
            float4 a = *(const float4*)&src[w][k];
            float4 c = *(const float4*)&src[w][k+4];
            acc[w] += a.x*wc[0] + a.y*wc[1] + a.z*wc[2] + a.w*wc[3]
                    + c.x*wc[4] + c.y*wc[5] + c.z*wc[6] + c.w*wc[7];
            part[w][half][n] = acc[w];
        }
    }
    __syncthreads();
    if (tid < E2) {
        float bb = bias[tid];
        #pragma unroll
        for (int w = 0; w < NW; ++w)
            dst[w][tid] = fmaxf(part[w][0][tid] + part[w][1][tid] + bb, 0.0f);
    }
    __syncthreads();
}

__global__ __launch_bounds__(NT, 4)
void beam_kernel(const int* __restrict__ g_nbe, const int* __restrict__ g_nbr,
                 const int* __restrict__ g_start, const int* __restrict__ g_tgt,
                 const float* __restrict__ g_ent, const float* __restrict__ g_rel,
                 const float* __restrict__ g_wx, const float* __restrict__ g_wh,
                 const float* __restrict__ g_lb, const float* __restrict__ g_w1,
                 const float* __restrict__ g_b1, const float* __restrict__ g_w2,
                 const float* __restrict__ g_b2, float* __restrict__ g_out)
{
    const int b   = blockIdx.x;
    const int tid = threadIdx.x;
    const int tgt = g_tgt[b];

    __shared__ __align__(16) float s_c[WW][EE];
    __shared__ __align__(16) float s_h[WW][EE];
    __shared__ __align__(16) float s_st[WW][E2];   // state in, also final feat
    __shared__ __align__(16) float s_fb[WW][E2];   // layer1 out
    __shared__ __align__(16) float s_x[WW][E2];    // selected candidate vectors
    __shared__ __align__(16) float s_pc[WW][EE];
    __shared__ __align__(16) float s_ph[WW][EE];
    __shared__ __align__(16) float s_gates[WW][E4];
    __shared__ __align__(16) float s_part[WW][2][E2];  // K-split partials
    __shared__ float s_probs[WW][DD];
    __shared__ int s_nbe[WW][DD];
    __shared__ int s_nbr[WW][DD];
    __shared__ int s_cur[WW], s_done[WW], s_sel[WW], s_newcur[WW], s_pdone[WW];

    // ---- init ----
    if (tid < WW) s_cur[tid] = g_start[b];
    for (int p = tid; p < WW*EE; p += NT) {
        int j = p / EE, e = p - j*EE;
        s_c[j][e] = 0.0f; s_h[j][e] = 0.0f;
    }
    __syncthreads();

    for (int t = 0; t < TT; ++t) {
        const bool t0 = (t == 0);   // all beams bitwise-identical at t==0

        // ---- A: done flags + neighbor row gather ----
        if (tid < WW) s_done[tid] = (s_cur[tid] == tgt) ? 1 : 0;
        if (tid < WW*DD) {
            int w = tid >> 6, d = tid & 63;
            int node = s_cur[w];
            s_nbe[w][d] = g_nbe[node*DD + d];
            s_nbr[w][d] = g_nbr[node*DD + d];
        }
        // ---- B0: state = [c || h] ----
        for (int p = tid; p < WW*E2; p += NT) {
            int w = p / E2, k = p - w*E2;
            s_st[w][k] = (k < EE) ? s_c[w][k] : s_h[w][k-EE];
        }
        __syncthreads();

        // ---- B1+B2: 2-layer MLP (beam 0 only at t==0; rows identical) ----
        if (t0) {
            mlp_layer<1>(g_w1, g_b1, s_st, s_part, s_fb, tid);
            mlp_layer<1>(g_w2, g_b2, s_fb, s_part, s_st, tid);
        } else {
            mlp_layer<WW>(g_w1, g_b1, s_st, s_part, s_fb, tid);
            mlp_layer<WW>(g_w2, g_b2, s_fb, s_part, s_st, tid);
        }

        // ---- C: scores[w][d] = cand . feat  (16 lanes/candidate, float4).
        //      Round-4 validated form; runtime trip count, no reg dbuf.
        {
            const int gid = tid >> 4;       // 0..63
            const int gl  = tid & 15;
            const int lim = (t0 ? 1 : WW) * DD;
            for (int p = gid; p < lim; p += 64) {
                int w = p >> 6, d = p & 63;
                const float* rrow = g_rel + s_nbr[w][d] * EE;
                const float* erow = g_ent + s_nbe[w][d] * EE;
                const float* fr = &s_st[w][0];
                float acc = 0.0f;
                #pragma unroll
                for (int i = 0; i < 3; ++i) {           // k = 0..191
                    int k = i*64 + gl*4;
                    float4 rv = *(const float4*)&rrow[k];
                    float4 ev = *(const float4*)&erow[k];
                    float4 f0 = *(const float4*)&fr[k];
                    float4 f1 = *(const float4*)&fr[EE + k];
                    acc += rv.x*f0.x + rv.y*f0.y + rv.z*f0.z + rv.w*f0.w;
                    acc += ev.x*f1.x + ev.y*f1.y + ev.z*f1.z + ev.w*f1.w;
                }
                if (gl < 8) {                           // k = 192..199
                    int k = 192 + gl;
                    acc += rrow[k] * fr[k] + erow[k] * fr[EE + k];
                }
                acc += __shfl_xor(acc, 8, 16);
                acc += __shfl_xor(acc, 4, 16);
                acc += __shfl_xor(acc, 2, 16);
                acc += __shfl_xor(acc, 1, 16);
                if (gl == 0) s_probs[w][d] = acc;
            }
        }
        __syncthreads();
        if (t0) {   // replicate raw score row 0 -> rows 1..4 (rows identical)
            if (tid < (WW-1)*DD) {
                int w = 1 + (tid >> 6);
                s_probs[w][tid & 63] = s_probs[0][tid & 63];
            }
            __syncthreads();
        }

        // ---- D+E: per-beam softmax + done masking + top-5 (wave 0) ----
        if (tid < 64) {
            const int lane = tid;
            float loc0, loc1, loc2, loc3, loc4;
            float locv[WW];
            #pragma unroll
            for (int w = 0; w < WW; ++w) {
                float v = s_probs[w][lane];
                float m = v;
                for (int off = 32; off; off >>= 1) m = fmaxf(m, __shfl_xor(m, off));
                float e = expf(v - m);
                float ssum = e;
                for (int off = 32; off; off >>= 1) ssum += __shfl_xor(ssum, off);
                float pr = e / ssum;
                if (s_done[w]) pr = (lane == 0) ? 2.0f : 0.0f;
                locv[w] = pr;
            }
            loc0 = locv[0]; loc1 = locv[1]; loc2 = locv[2]; loc3 = locv[3]; loc4 = locv[4];
            #pragma unroll
            for (int j = 0; j < WW; ++j) {
                float bv = -1.0f; int bi = 0x7fffffff;
                { float v = loc0; int p = 0*DD + lane; if (v > bv) { bv = v; bi = p; } }
                { float v = loc1; int p = 1*DD + lane; if (v > bv) { bv = v; bi = p; } }
                { float v = loc2; int p = 2*DD + lane; if (v > bv) { bv = v; bi = p; } }
                { float v = loc3; int p = 3*DD + lane; if (v > bv) { bv = v; bi = p; } }
                { float v = loc4; int p = 4*DD + lane; if (v > bv) { bv = v; bi = p; } }
                for (int off = 32; off; off >>= 1) {
                    float ov = __shfl_xor(bv, off);
                    int   oi = __shfl_xor(bi, off);
                    if (ov > bv || (ov == bv && oi < bi)) { bv = ov; bi = oi; }
                }
                if (lane == 0) s_sel[j] = bi;
                bool mine = (bi & 63) == lane;
                int bw = bi >> 6;
                if (mine && bw == 0) loc0 = -4.0f;
                if (mine && bw == 1) loc1 = -4.0f;
                if (mine && bw == 2) loc2 = -4.0f;
                if (mine && bw == 3) loc3 = -4.0f;
                if (mine && bw == 4) loc4 = -4.0f;
            }
        }
        __syncthreads();

        // ---- F: gather selection (x, parent c/h, new cur) ----
        if (tid < WW) {
            int j = tid;
            int fi = s_sel[j];
            int pw = fi >> 6, d = fi & 63;
            int pd = s_done[pw];
            s_pdone[j] = pd;
            s_newcur[j] = pd ? s_cur[pw] : s_nbe[pw][d];
        }
        for (int p = tid; p < WW*E2; p += NT) {
            int j = p / E2, k = p - j*E2;
            int fi = s_sel[j];
            int pw = fi >> 6, d = fi & 63;
            float v;
            if (k < EE) v = g_rel[s_nbr[pw][d]*EE + k];
            else        v = g_ent[s_nbe[pw][d]*EE + (k-EE)];
            s_x[j][k] = v;
        }
        for (int p = tid; p < WW*EE; p += NT) {
            int j = p / EE, e = p - j*EE;
            int pw = s_sel[j] >> 6;
            s_pc[j][e] = s_c[pw][e];
            s_ph[j][e] = s_h[pw][e];
        }
        __syncthreads();

        // ---- G: LSTM gates = x @ Wx + ph @ Wh + b (800 thr, static prefetch;
        //          Wh skipped at t==0 since ph == 0 exactly) ----
        if (tid < E4) {
            const int n = tid;
            float acc[WW];
            #pragma unroll
            for (int w = 0; w < WW; ++w) acc[w] = g_lb[n];
            {   // Wx part: K = E2
                const float* wp = g_wx + n;
                float wc[8], wn[8];
                #pragma unroll
                for (int i = 0; i < 8; ++i) wc[i] = wp[i*E4];
                int k = 0;
                for (int kk = 0; kk < E2/8 - 1; ++kk) {
                    wp += 8*E4;
                    #pragma unroll
                    for (int i = 0; i < 8; ++i) wn[i] = wp[i*E4];
                    #pragma unroll
                    for (int w = 0; w < WW; ++w) {
                        float4 a = *(const float4*)&s_x[w][k];
                        float4 c = *(const float4*)&s_x[w][k+4];
                        acc[w] += a.x*wc[0] + a.y*wc[1] + a.z*wc[2] + a.w*wc[3]
                                + c.x*wc[4] + c.y*wc[5] + c.z*wc[6] + c.w*wc[7];
                    }
                    #pragma unroll
                    for (int i = 0; i < 8; ++i) wc[i] = wn[i];
                    k += 8;
                }
                #pragma unroll
                for (int w = 0; w < WW; ++w) {
                    float4 a = *(const float4*)&s_x[w][k];
                    float4 c = *(const float4*)&s_x[w][k+4];
                    acc[w] += a.x*wc[0] + a.y*wc[1] + a.z*wc[2] + a.w*wc[3]
                            + c.x*wc[4] + c.y*wc[5] + c.z*wc[6] + c.w*wc[7];
                }
            }
            if (!t0) {  // Wh part: K = EE  (ph==0 at t0 -> exact zeros)
                const float* wp = g_wh + n;
                float wc[8], wn[8];
                #pragma unroll
                for (int i = 0; i < 8; ++i) wc[i] = wp[i*E4];
                int k = 0;
                for (int kk = 0; kk < EE/8 - 1; ++kk) {
                    wp += 8*E4;
                    #pragma unroll
                    for (int i = 0; i < 8; ++i) wn[i] = wp[i*E4];
                    #pragma unroll
                    for (int w = 0; w < WW; ++w) {
                        float4 a = *(const float4*)&s_ph[w][k];
                        float4 c = *(const float4*)&s_ph[w][k+4];
                        acc[w] += a.x*wc[0] + a.y*wc[1] + a.z*wc[2] + a.w*wc[3]
                                + c.x*wc[4] + c.y*wc[5] + c.z*wc[6] + c.w*wc[7];
                    }
                    #pragma unroll
                    for (int i = 0; i < 8; ++i) wc[i] = wn[i];
                    k += 8;
                }
                #pragma unroll
                for (int w = 0; w < WW; ++w) {
                    float4 a = *(const float4*)&s_ph[w][k];
                    float4 c = *(const float4*)&s_ph[w][k+4];
                    acc[w] += a.x*wc[0] + a.y*wc[1] + a.z*wc[2] + a.w*wc[3]
                            + c.x*wc[4] + c.y*wc[5] + c.z*wc[6] + c.w*wc[7];
                }
            }
            #pragma unroll
            for (int w = 0; w < WW; ++w) s_gates[w][n] = acc[w];
        }
        __syncthreads();

        // ---- H: LSTM pointwise + freeze + cur update ----
        for (int p = tid; p < WW*EE; p += NT) {
            int j = p / EE, e = p - j*EE;
            float gi = s_gates[j][e];
            float gf = s_gates[j][EE + e];
            float go = s_gates[j][2*EE + e];
            float gg = s_gates[j][3*EE + e];
            float pcv = s_pc[j][e], phv = s_ph[j][e];
            float nc = sigf(gf)*pcv + sigf(gi)*tanhf(gg);
            float nh = sigf(go)*tanhf(nc);
            if (s_pdone[j]) { nc = pcv; nh = phv; }
            s_c[j][e] = nc;
            s_h[j][e] = nh;
        }
        if (tid < WW) s_cur[tid] = s_newcur[tid];
        __syncthreads();
    }

    // ---- output: h [B,W,E] then cur [B,W] as float ----
    for (int p = tid; p < WW*EE; p += NT) {
        int j = p / EE, e = p - j*EE;
        g_out[b*(WW*EE) + j*EE + e] = s_h[j][e];
    }
    if (tid < WW) g_out[BB*WW*EE + b*WW + tid] = (float)s_cur[tid];
}

extern "C" void kernel_launch(void* const* d_in, const int* in_sizes, int n_in,
                              void* d_out, int out_size, void* d_ws, size_t ws_size,
                              hipStream_t stream) {
    const int*   nbe   = (const int*)d_in[0];
    const int*   nbr   = (const int*)d_in[1];
    const int*   start = (const int*)d_in[2];
    const int*   tgt   = (const int*)d_in[3];
    const float* ent   = (const float*)d_in[4];
    const float* rel   = (const float*)d_in[5];
    const float* wx    = (const float*)d_in[6];
    const float* wh    = (const float*)d_in[7];
    const float* lb    = (const float*)d_in[8];
    const float* w1    = (const float*)d_in[9];
    const float* b1    = (const float*)d_in[10];
    const float* w2    = (const float*)d_in[11];
    const float* b2    = (const float*)d_in[12];
    float* out = (float*)d_out;

    hipLaunchKernelGGL(beam_kernel, dim3(BB), dim3(NT), 0, stream,
                       nbe, nbr, start, tgt, ent, rel, wx, wh, lb, w1, b1, w2, b2, out);
}

// Round 11
// 597.703 us; speedup vs baseline: 1.6689x; 1.6689x over previous
//
#include <hip/hip_runtime.h>

#define NN 100000
#define RR 1000
#define DD 64
#define EE 200
#define BB 256
#define WW 5
#define TT 5
#define E2 400
#define E4 800
#define NT 1024

__device__ __forceinline__ float sigf(float x) { return 1.0f / (1.0f + expf(-x)); }

__global__ __launch_bounds__(NT, 4)
void beam_kernel(const int* __restrict__ g_nbe, const int* __restrict__ g_nbr,
                 const int* __restrict__ g_start, const int* __restrict__ g_tgt,
                 const float* __restrict__ g_ent, const float* __restrict__ g_rel,
                 const float* __restrict__ g_wx, const float* __restrict__ g_wh,
                 const float* __restrict__ g_lb, const float* __restrict__ g_w1,
                 const float* __restrict__ g_b1, const float* __restrict__ g_w2,
                 const float* __restrict__ g_b2, float* __restrict__ g_out)
{
    const int b   = blockIdx.x;
    const int tid = threadIdx.x;
    const int tgt = g_tgt[b];

    __shared__ __align__(16) float s_c[WW][EE];
    __shared__ __align__(16) float s_h[WW][EE];
    __shared__ __align__(16) float s_st[WW][E2];   // state in, also final feat
    __shared__ __align__(16) float s_fb[WW][E2];   // layer1 out
    __shared__ __align__(16) float s_x[WW][E2];    // selected candidate vectors
    __shared__ __align__(16) float s_pc[WW][EE];
    __shared__ __align__(16) float s_ph[WW][EE];
    __shared__ __align__(16) float s_gates[WW][E4];
    __shared__ __align__(16) float s_part[WW][2][E2];  // K-split partials
    __shared__ float s_probs[WW][DD];
    __shared__ int s_nbe[WW][DD];
    __shared__ int s_nbr[WW][DD];
    __shared__ int s_cur[WW], s_done[WW], s_sel[WW], s_newcur[WW], s_pdone[WW];

    // ---- init ----
    if (tid < WW) s_cur[tid] = g_start[b];
    for (int p = tid; p < WW*EE; p += NT) {
        int j = p / EE, e = p - j*EE;
        s_c[j][e] = 0.0f; s_h[j][e] = 0.0f;
    }
    __syncthreads();

    for (int t = 0; t < TT; ++t) {
        // ---- A: done flags + neighbor row gather ----
        if (tid < WW) s_done[tid] = (s_cur[tid] == tgt) ? 1 : 0;
        if (tid < WW*DD) {
            int w = tid >> 6, d = tid & 63;
            int node = s_cur[w];
            s_nbe[w][d] = g_nbe[node*DD + d];
            s_nbr[w][d] = g_nbr[node*DD + d];
        }
        // ---- B0: state = [c || h] ----
        for (int p = tid; p < WW*E2; p += NT) {
            int w = p / E2, k = p - w*E2;
            s_st[w][k] = (k < EE) ? s_c[w][k] : s_h[w][k-EE];
        }
        __syncthreads();

        // ---- B1: MLP layer 1, K-split x2 (800 threads), unroll-8 ----
        if (tid < 2*E2) {
            const int half = tid / E2;
            const int n    = tid - half*E2;
            const int k0   = half * (E2/2);
            float acc[WW];
            #pragma unroll
            for (int w = 0; w < WW; ++w) acc[w] = 0.0f;
            for (int kk = 0; kk < (E2/2)/8; ++kk) {
                int k = k0 + kk*8;
                float wv0 = g_w1[(k+0)*E2+n];
                float wv1 = g_w1[(k+1)*E2+n];
                float wv2 = g_w1[(k+2)*E2+n];
                float wv3 = g_w1[(k+3)*E2+n];
                float wv4 = g_w1[(k+4)*E2+n];
                float wv5 = g_w1[(k+5)*E2+n];
                float wv6 = g_w1[(k+6)*E2+n];
                float wv7 = g_w1[(k+7)*E2+n];
                #pragma unroll
                for (int w = 0; w < WW; ++w) {
                    float4 a = *(const float4*)&s_st[w][k];
                    float4 c = *(const float4*)&s_st[w][k+4];
                    acc[w] += a.x*wv0 + a.y*wv1 + a.z*wv2 + a.w*wv3
                            + c.x*wv4 + c.y*wv5 + c.z*wv6 + c.w*wv7;
                }
            }
            #pragma unroll
            for (int w = 0; w < WW; ++w) s_part[w][half][n] = acc[w];
        }
        __syncthreads();
        if (tid < E2) {
            float bb = g_b1[tid];
            #pragma unroll
            for (int w = 0; w < WW; ++w)
                s_fb[w][tid] = fmaxf(s_part[w][0][tid] + s_part[w][1][tid] + bb, 0.0f);
        }
        __syncthreads();

        // ---- B2: MLP layer 2, K-split x2 ----
        if (tid < 2*E2) {
            const int half = tid / E2;
            const int n    = tid - half*E2;
            const int k0   = half * (E2/2);
            float acc[WW];
            #pragma unroll
            for (int w = 0; w < WW; ++w) acc[w] = 0.0f;
            for (int kk = 0; kk < (E2/2)/8; ++kk) {
                int k = k0 + kk*8;
                float wv0 = g_w2[(k+0)*E2+n];
                float wv1 = g_w2[(k+1)*E2+n];
                float wv2 = g_w2[(k+2)*E2+n];
                float wv3 = g_w2[(k+3)*E2+n];
                float wv4 = g_w2[(k+4)*E2+n];
                float wv5 = g_w2[(k+5)*E2+n];
                float wv6 = g_w2[(k+6)*E2+n];
                float wv7 = g_w2[(k+7)*E2+n];
                #pragma unroll
                for (int w = 0; w < WW; ++w) {
                    float4 a = *(const float4*)&s_fb[w][k];
                    float4 c = *(const float4*)&s_fb[w][k+4];
                    acc[w] += a.x*wv0 + a.y*wv1 + a.z*wv2 + a.w*wv3
                            + c.x*wv4 + c.y*wv5 + c.z*wv6 + c.w*wv7;
                }
            }
            #pragma unroll
            for (int w = 0; w < WW; ++w) s_part[w][half][n] = acc[w];
        }
        __syncthreads();
        if (tid < E2) {
            float bb = g_b2[tid];
            #pragma unroll
            for (int w = 0; w < WW; ++w)
                s_st[w][tid] = fmaxf(s_part[w][0][tid] + s_part[w][1][tid] + bb, 0.0f);
        }
        __syncthreads();

        // ---- C: scores[w][d] = cand . feat  (16 lanes/candidate, float4).
        //      t==0: all beam rows identical -> compute row 0 only.
        {
            const int gid = tid >> 4;       // 0..63
            const int gl  = tid & 15;
            const int lim = (t == 0) ? DD : WW*DD;
            for (int p = gid; p < lim; p += 64) {
                int w = p >> 6, d = p & 63;
                const float* rrow = g_rel + s_nbr[w][d] * EE;
                const float* erow = g_ent + s_nbe[w][d] * EE;
                const float* fr = &s_st[w][0];
                float acc = 0.0f;
                #pragma unroll
                for (int i = 0; i < 3; ++i) {           // k = 0..191
                    int k = i*64 + gl*4;
                    float4 rv = *(const float4*)&rrow[k];
                    float4 ev = *(const float4*)&erow[k];
                    float4 f0 = *(const float4*)&fr[k];
                    float4 f1 = *(const float4*)&fr[EE + k];
                    acc += rv.x*f0.x + rv.y*f0.y + rv.z*f0.z + rv.w*f0.w;
                    acc += ev.x*f1.x + ev.y*f1.y + ev.z*f1.z + ev.w*f1.w;
                }
                if (gl < 8) {                           // k = 192..199
                    int k = 192 + gl;
                    acc += rrow[k] * fr[k] + erow[k] * fr[EE + k];
                }
                acc += __shfl_xor(acc, 8, 16);
                acc += __shfl_xor(acc, 4, 16);
                acc += __shfl_xor(acc, 2, 16);
                acc += __shfl_xor(acc, 1, 16);
                if (gl == 0) s_probs[w][d] = acc;
            }
        }
        __syncthreads();
        if (t == 0) {   // replicate raw score row 0 -> rows 1..4 (identical)
            if (tid < (WW-1)*DD) {
                int w = 1 + (tid >> 6);
                s_probs[w][tid & 63] = s_probs[0][tid & 63];
            }
            __syncthreads();
        }

        // ---- D+E: per-beam softmax + done masking + top-5 (wave 0) ----
        if (tid < 64) {
            const int lane = tid;
            float loc0, loc1, loc2, loc3, loc4;
            float locv[WW];
            #pragma unroll
            for (int w = 0; w < WW; ++w) {
                float v = s_probs[w][lane];
                float m = v;
                for (int off = 32; off; off >>= 1) m = fmaxf(m, __shfl_xor(m, off));
                float e = expf(v - m);
                float ssum = e;
                for (int off = 32; off; off >>= 1) ssum += __shfl_xor(ssum, off);
                float pr = e / ssum;
                if (s_done[w]) pr = (lane == 0) ? 2.0f : 0.0f;
                locv[w] = pr;
            }
            loc0 = locv[0]; loc1 = locv[1]; loc2 = locv[2]; loc3 = locv[3]; loc4 = locv[4];
            #pragma unroll
            for (int j = 0; j < WW; ++j) {
                float bv = -1.0f; int bi = 0x7fffffff;
                { float v = loc0; int p = 0*DD + lane; if (v > bv) { bv = v; bi = p; } }
                { float v = loc1; int p = 1*DD + lane; if (v > bv) { bv = v; bi = p; } }
                { float v = loc2; int p = 2*DD + lane; if (v > bv) { bv = v; bi = p; } }
                { float v = loc3; int p = 3*DD + lane; if (v > bv) { bv = v; bi = p; } }
                { float v = loc4; int p = 4*DD + lane; if (v > bv) { bv = v; bi = p; } }
                for (int off = 32; off; off >>= 1) {
                    float ov = __shfl_xor(bv, off);
                    int   oi = __shfl_xor(bi, off);
                    if (ov > bv || (ov == bv && oi < bi)) { bv = ov; bi = oi; }
                }
                if (lane == 0) s_sel[j] = bi;
                bool mine = (bi & 63) == lane;
                int bw = bi >> 6;
                if (mine && bw == 0) loc0 = -4.0f;
                if (mine && bw == 1) loc1 = -4.0f;
                if (mine && bw == 2) loc2 = -4.0f;
                if (mine && bw == 3) loc3 = -4.0f;
                if (mine && bw == 4) loc4 = -4.0f;
            }
        }
        __syncthreads();

        // ---- F: gather selection (x, parent c/h, new cur) ----
        if (tid < WW) {
            int j = tid;
            int fi = s_sel[j];
            int pw = fi >> 6, d = fi & 63;
            int pd = s_done[pw];
            s_pdone[j] = pd;
            s_newcur[j] = pd ? s_cur[pw] : s_nbe[pw][d];
        }
        for (int p = tid; p < WW*E2; p += NT) {
            int j = p / E2, k = p - j*E2;
            int fi = s_sel[j];
            int pw = fi >> 6, d = fi & 63;
            float v;
            if (k < EE) v = g_rel[s_nbr[pw][d]*EE + k];
            else        v = g_ent[s_nbe[pw][d]*EE + (k-EE)];
            s_x[j][k] = v;
        }
        for (int p = tid; p < WW*EE; p += NT) {
            int j = p / EE, e = p - j*EE;
            int pw = s_sel[j] >> 6;
            s_pc[j][e] = s_c[pw][e];
            s_ph[j][e] = s_h[pw][e];
        }
        __syncthreads();

        // ---- G: LSTM gates = x @ Wx + ph @ Wh + b  (800 threads, 1 col;
        //          Wh loop skipped at t==0 since ph == 0 exactly) ----
        if (tid < E4) {
            const int n = tid;
            float acc[WW];
            #pragma unroll
            for (int w = 0; w < WW; ++w) acc[w] = g_lb[n];
            for (int kk = 0; kk < E2/8; ++kk) {
                int k = kk*8;
                float wv0 = g_wx[(k+0)*E4+n];
                float wv1 = g_wx[(k+1)*E4+n];
                float wv2 = g_wx[(k+2)*E4+n];
                float wv3 = g_wx[(k+3)*E4+n];
                float wv4 = g_wx[(k+4)*E4+n];
                float wv5 = g_wx[(k+5)*E4+n];
                float wv6 = g_wx[(k+6)*E4+n];
                float wv7 = g_wx[(k+7)*E4+n];
                #pragma unroll
                for (int w = 0; w < WW; ++w) {
                    float4 a = *(const float4*)&s_x[w][k];
                    float4 c = *(const float4*)&s_x[w][k+4];
                    acc[w] += a.x*wv0 + a.y*wv1 + a.z*wv2 + a.w*wv3
                            + c.x*wv4 + c.y*wv5 + c.z*wv6 + c.w*wv7;
                }
            }
            if (t != 0) {
                for (int kk = 0; kk < EE/8; ++kk) {
                    int k = kk*8;
                    float wv0 = g_wh[(k+0)*E4+n];
                    float wv1 = g_wh[(k+1)*E4+n];
                    float wv2 = g_wh[(k+2)*E4+n];
                    float wv3 = g_wh[(k+3)*E4+n];
                    float wv4 = g_wh[(k+4)*E4+n];
                    float wv5 = g_wh[(k+5)*E4+n];
                    float wv6 = g_wh[(k+6)*E4+n];
                    float wv7 = g_wh[(k+7)*E4+n];
                    #pragma unroll
                    for (int w = 0; w < WW; ++w) {
                        float4 a = *(const float4*)&s_ph[w][k];
                        float4 c = *(const float4*)&s_ph[w][k+4];
                        acc[w] += a.x*wv0 + a.y*wv1 + a.z*wv2 + a.w*wv3
                                + c.x*wv4 + c.y*wv5 + c.z*wv6 + c.w*wv7;
                    }
                }
            }
            #pragma unroll
            for (int w = 0; w < WW; ++w) s_gates[w][n] = acc[w];
        }
        __syncthreads();

        // ---- H: LSTM pointwise + freeze + cur update ----
        for (int p = tid; p < WW*EE; p += NT) {
            int j = p / EE, e = p - j*EE;
            float gi = s_gates[j][e];
            float gf = s_gates[j][EE + e];
            float go = s_gates[j][2*EE + e];
            float gg = s_gates[j][3*EE + e];
            float pcv = s_pc[j][e], phv = s_ph[j][e];
            float nc = sigf(gf)*pcv + sigf(gi)*tanhf(gg);
            float nh = sigf(go)*tanhf(nc);
            if (s_pdone[j]) { nc = pcv; nh = phv; }
            s_c[j][e] = nc;
            s_h[j][e] = nh;
        }
        if (tid < WW) s_cur[tid] = s_newcur[tid];
        __syncthreads();
    }

    // ---- output: h [B,W,E] then cur [B,W] as float ----
    for (int p = tid; p < WW*EE; p += NT) {
        int j = p / EE, e = p - j*EE;
        g_out[b*(WW*EE) + j*EE + e] = s_h[j][e];
    }
    if (tid < WW) g_out[BB*WW*EE + b*WW + tid] = (float)s_cur[tid];
}

extern "C" void kernel_launch(void* const* d_in, const int* in_sizes, int n_in,
                              void* d_out, int out_size, void* d_ws, size_t ws_size,
                              hipStream_t stream) {
    const int*   nbe   = (const int*)d_in[0];
    const int*   nbr   = (const int*)d_in[1];
    const int*   start = (const int*)d_in[2];
    const int*   tgt   = (const int*)d_in[3];
    const float* ent   = (const float*)d_in[4];
    const float* rel   = (const float*)d_in[5];
    const float* wx    = (const float*)d_in[6];
    const float* wh    = (const float*)d_in[7];
    const float* lb    = (const float*)d_in[8];
    const float* w1    = (const float*)d_in[9];
    const float* b1    = (const float*)d_in[10];
    const float* w2    = (const float*)d_in[11];
    const float* b2    = (const float*)d_in[12];
    float* out = (float*)d_out;

    hipLaunchKernelGGL(beam_kernel, dim3(BB), dim3(NT), 0, stream,
                       nbe, nbr, start, tgt, ent, rel, wx, wh, lb, w1, b1, w2, b2, out);
}